// Round 4
// baseline (232.240 us; speedup 1.0000x reference)
//
#include <hip/hip_runtime.h>

#define SEQ 41
#define FEAT 128
#define KDIM 384
#define ROWLEN (SEQ * FEAT)        // 5248 floats per batch row
#define BM 128

typedef float floatx4 __attribute__((ext_vector_type(4)));
typedef __bf16 bf16x8 __attribute__((ext_vector_type(8)));
typedef unsigned short ushortx4 __attribute__((ext_vector_type(4)));
typedef unsigned short ushortx8 __attribute__((ext_vector_type(8)));

// fp32 -> bf16 via hardware cvt (RNE on gfx950)
__device__ __forceinline__ unsigned short f2bf(float f) {
    return __builtin_bit_cast(unsigned short, (__bf16)f);
}

// ---------------- prepass: W[s][k][n] -> Wt fragment order, LDS transpose ------
// One block per (s, slab). Coalesced float4 reads, coalesced 16B frag writes.
// Wt linear: [s*6+slab][ks(2)][nt(8)][lane(64)][8 bf16]
//   n = nt*16 + (lane&15);  k = slab*64 + ks*32 + (lane>>4)*8 + j
__global__ __launch_bounds__(256) void wt3_kernel(const float* __restrict__ W,
                                                  unsigned short* __restrict__ Wt) {
    __shared__ float tile[64][FEAT + 1];
    const int tid = threadIdx.x;
    const int s = blockIdx.x / 6, slab = blockIdx.x % 6;
    const float* src = W + ((size_t)s * KDIM + slab * 64) * FEAT;
#pragma unroll
    for (int p = 0; p < 8; p++) {
        int q  = p * 256 + tid;          // float4 id, 2048 total
        int k  = q >> 5;
        int n4 = (q & 31) * 4;
        floatx4 v = *reinterpret_cast<const floatx4*>(src + (size_t)k * FEAT + n4);
        tile[k][n4] = v[0]; tile[k][n4 + 1] = v[1];
        tile[k][n4 + 2] = v[2]; tile[k][n4 + 3] = v[3];
    }
    __syncthreads();
    unsigned short* dst = Wt + (size_t)blockIdx.x * 8192;
#pragma unroll
    for (int p = 0; p < 4; p++) {
        int g = p * 256 + tid;           // frag slot id: ks*512 + nt*64 + lane
        int lane = g & 63, nt = (g >> 6) & 7, ks = g >> 9;
        int n  = nt * 16 + (lane & 15);
        int k0 = ks * 32 + (lane >> 4) * 8;
        ushortx8 v;
#pragma unroll
        for (int j = 0; j < 8; j++) v[j] = f2bf(tile[k0 + j][n]);
        *reinterpret_cast<ushortx8*>(dst + (size_t)g * 8) = v;
    }
}

// ---------------- main GEMM ----------------
// 256 thr = 4 waves (2x2). Tile 128m x 128n x K=384. A: LDS dbuf (32 KB total,
// fragment order, conflict-free reads). B: registers, direct coalesced loads
// from fragment-ordered Wt (L2-resident). Fully unrolled 6-slab K loop,
// one barrier per slab. Edge-s invalid slabs feed zero A (no divergence).
template <int USE_WT>
__global__ __launch_bounds__(256, 3) void gemm_kernel(const float* __restrict__ X,
                                                      const void* __restrict__ Wsrc,
                                                      const float* __restrict__ bias,
                                                      float* __restrict__ out) {
    __shared__ unsigned short Afrag[2][2][8][512];   // [buf][ks][mtile][lane*8]

    const int tid  = threadIdx.x;
    const int lane = tid & 63;
    const int wv   = tid >> 6;
    const int s    = blockIdx.y;
    const int m0   = blockIdx.x * BM;
    const int obase = (s - 1) * FEAT;

    const int wr = wv >> 1, wc = wv & 1;
    const int colq = lane & 15, quad = lane >> 4;
    const int ar = tid >> 3, ag = tid & 7;
    const int aq = ag >> 1, ahalf = ag & 1;

    const unsigned short* Wt = (const unsigned short*)Wsrc;
    const float* Wf = (const float*)Wsrc;

    floatx4 acc[4][4];
#pragma unroll
    for (int i = 0; i < 4; i++)
#pragma unroll
        for (int j = 0; j < 4; j++) acc[i][j] = (floatx4){0.f, 0.f, 0.f, 0.f};

    floatx4 a0[4], a1[4];
    bf16x8 bq[2][4];                                  // [ks][ni], current slab

    auto stageA_load = [&](int slab) {
        bool valid = !((s == 0 && slab < 2) || (s == SEQ - 1 && slab >= 4));
        if (valid) {
#pragma unroll
            for (int p = 0; p < 4; p++) {
                const float* base = X + (size_t)(m0 + p * 32 + ar) * ROWLEN
                                      + obase + slab * 64 + ag * 4;
                a0[p] = *reinterpret_cast<const floatx4*>(base);
                a1[p] = *reinterpret_cast<const floatx4*>(base + 32);
            }
        } else {
#pragma unroll
            for (int p = 0; p < 4; p++) {
                a0[p] = (floatx4){0.f, 0.f, 0.f, 0.f};
                a1[p] = (floatx4){0.f, 0.f, 0.f, 0.f};
            }
        }
    };
    auto stageA_write = [&](int buf) {
#pragma unroll
        for (int p = 0; p < 4; p++) {
            int r  = p * 32 + ar;
            int mt = r >> 4;
            int sl = ((r & 15) + 16 * aq) * 8 + ahalf * 4;
            ushortx4 w0, w1;
#pragma unroll
            for (int e = 0; e < 4; e++) { w0[e] = f2bf(a0[p][e]); w1[e] = f2bf(a1[p][e]); }
            *reinterpret_cast<ushortx4*>(&Afrag[buf][0][mt][sl]) = w0;
            *reinterpret_cast<ushortx4*>(&Afrag[buf][1][mt][sl]) = w1;
        }
    };
    auto loadB = [&](int slab) {
        if (USE_WT) {
            const unsigned short* src = Wt + ((size_t)(s * 6 + slab)) * 8192 + lane * 8;
#pragma unroll
            for (int ks = 0; ks < 2; ks++)
#pragma unroll
                for (int ni = 0; ni < 4; ni++)
                    bq[ks][ni] = *reinterpret_cast<const bf16x8*>(
                        src + (ks * 8 + wc * 4 + ni) * 512);
        } else {
            // correctness fallback: gather from fp32 W[s][k][n]
#pragma unroll
            for (int ks = 0; ks < 2; ks++)
#pragma unroll
                for (int ni = 0; ni < 4; ni++) {
                    int n = (wc * 4 + ni) * 16 + colq;
                    int k = slab * 64 + ks * 32 + quad * 8;
                    ushortx8 v;
#pragma unroll
                    for (int j = 0; j < 8; j++)
                        v[j] = f2bf(Wf[((size_t)s * KDIM + k + j) * FEAT + n]);
                    bq[ks][ni] = __builtin_bit_cast(bf16x8, v);
                }
        }
    };
    auto compute = [&](int buf) {
#pragma unroll
        for (int ks = 0; ks < 2; ks++) {
            bf16x8 af[4];
#pragma unroll
            for (int i = 0; i < 4; i++)
                af[i] = *reinterpret_cast<const bf16x8*>(
                    &Afrag[buf][ks][wr * 4 + i][lane * 8]);
#pragma unroll
            for (int mi = 0; mi < 4; mi++)
#pragma unroll
                for (int ni = 0; ni < 4; ni++)
                    acc[mi][ni] = __builtin_amdgcn_mfma_f32_16x16x32_bf16(
                        af[mi], bq[ks][ni], acc[mi][ni], 0, 0, 0);
        }
    };

    // prologue: stage slab 0 into buffer 0
    stageA_load(0);
    stageA_write(0);

#pragma unroll
    for (int i = 0; i < 6; i++) {
        __syncthreads();                  // A[buf i&1] visible to all waves
        loadB(i);                         // coalesced, L2-hit; consumed below
        if (i < 5) stageA_load(i + 1);    // issue next slab's global loads
        compute(i & 1);                   // 8 ds_read_b128 + 32 MFMA
        if (i < 5) stageA_write((i + 1) & 1);  // cvt + write other buffer
    }

    // epilogue: bias + relu; C layout: col=lane&15, row=quad*4+reg (verified)
#pragma unroll
    for (int mi = 0; mi < 4; mi++) {
        int m = m0 + (wr * 4 + mi) * 16 + quad * 4;
#pragma unroll
        for (int ni = 0; ni < 4; ni++) {
            int n = (wc * 4 + ni) * 16 + colq;
            float bv = bias[s * FEAT + n];
#pragma unroll
            for (int r = 0; r < 4; r++) {
                float v = acc[mi][ni][r] + bv;
                v = v > 0.f ? v : 0.f;
                out[((size_t)(m + r) * SEQ + s) * FEAT + n] = v;
            }
        }
    }
}

extern "C" void kernel_launch(void* const* d_in, const int* in_sizes, int n_in,
                              void* d_out, int out_size, void* d_ws, size_t ws_size,
                              hipStream_t stream) {
    const float* X    = (const float*)d_in[0];
    const float* W    = (const float*)d_in[1];
    const float* bias = (const float*)d_in[2];
    float* out = (float*)d_out;

    const int B = in_sizes[0] / ROWLEN;               // 4096
    dim3 grid(B / BM, SEQ);                           // m-fastest: same-s blocks adjacent

    const size_t wt_bytes = (size_t)SEQ * 6 * 8192 * sizeof(unsigned short);  // ~4 MB
    if (ws_size >= wt_bytes) {
        unsigned short* Wt = (unsigned short*)d_ws;
        wt3_kernel<<<SEQ * 6, 256, 0, stream>>>(W, Wt);
        gemm_kernel<1><<<grid, 256, 0, stream>>>(X, (const void*)Wt, bias, out);
    } else {
        gemm_kernel<0><<<grid, 256, 0, stream>>>(X, (const void*)W, bias, out);
    }
}

// Round 5
// 219.760 us; speedup vs baseline: 1.0568x; 1.0568x over previous
//
#include <hip/hip_runtime.h>

#define SEQ 41
#define FEAT 128
#define KDIM 384
#define ROWLEN (SEQ * FEAT)        // 5248 floats per batch row
#define BM 64                      // rows per block (2 m-waves x 32 rows? no: 2x2 below)

typedef float floatx4 __attribute__((ext_vector_type(4)));
typedef __bf16 bf16x8 __attribute__((ext_vector_type(8)));
typedef unsigned short ushortx8 __attribute__((ext_vector_type(8)));

// fp32 -> bf16 via hardware cvt (RNE on gfx950)
__device__ __forceinline__ unsigned short f2bf(float f) {
    return __builtin_bit_cast(unsigned short, (__bf16)f);
}

// ---------------- prepass: W[s][k][n] -> Wt fragment order, LDS transpose ------
// Wt linear: [s*6+slab][ks(2)][nt(8)][lane(64)][8 bf16]
//   n = nt*16 + (lane&15);  k = slab*64 + ks*32 + (lane>>4)*8 + j
__global__ __launch_bounds__(256) void wt3_kernel(const float* __restrict__ W,
                                                  unsigned short* __restrict__ Wt) {
    __shared__ float tile[64][FEAT + 1];
    const int tid = threadIdx.x;
    const int s = blockIdx.x / 6, slab = blockIdx.x % 6;
    const float* src = W + ((size_t)s * KDIM + slab * 64) * FEAT;
#pragma unroll
    for (int p = 0; p < 8; p++) {
        int q  = p * 256 + tid;
        int k  = q >> 5;
        int n4 = (q & 31) * 4;
        floatx4 v = *reinterpret_cast<const floatx4*>(src + (size_t)k * FEAT + n4);
        tile[k][n4] = v[0]; tile[k][n4 + 1] = v[1];
        tile[k][n4 + 2] = v[2]; tile[k][n4 + 3] = v[3];
    }
    __syncthreads();
    unsigned short* dst = Wt + (size_t)blockIdx.x * 8192;
#pragma unroll
    for (int p = 0; p < 4; p++) {
        int g = p * 256 + tid;           // frag slot id: ks*512 + nt*64 + lane
        int lane = g & 63, nt = (g >> 6) & 7, ks = g >> 9;
        int n  = nt * 16 + (lane & 15);
        int k0 = ks * 32 + (lane >> 4) * 8;
        ushortx8 v;
#pragma unroll
        for (int j = 0; j < 8; j++) v[j] = f2bf(tile[k0 + j][n]);
        *reinterpret_cast<ushortx8*>(dst + (size_t)g * 8) = v;
    }
}

// ---------------- main GEMM: barrier-free, wave-private A staging ----------------
// Block 256 thr = 4 waves in 2x2: wave (wm,wn) computes rows m0+wm*32..+31,
// cols wn*64..+63. Each wave stages its OWN A rows into a private LDS region
// (fragment order, dbuf) -> no __syncthreads anywhere. B fragments are loaded
// directly from L2-resident fragment-ordered Wt (coalesced lane*16B).
template <int USE_WT>
__global__ __launch_bounds__(256, 2) void gemm_kernel(const float* __restrict__ X,
                                                      const void* __restrict__ Wsrc,
                                                      const float* __restrict__ bias,
                                                      float* __restrict__ out) {
    // [wave][buf][ks][mt][lane'(64) * 8 bf16]  -> 4*2*2*2*1024 B = 32 KB
    __shared__ unsigned short Alds[4][2][2][2][512];

    const int tid  = threadIdx.x;
    const int lane = tid & 63;
    const int wv   = tid >> 6;
    const int wm   = wv >> 1, wn = wv & 1;
    const int s    = blockIdx.y;
    const int m0   = blockIdx.x * BM;
    const int obase = (s - 1) * FEAT;

    const int colq = lane & 15, quad = lane >> 4;

    // A staging lane constants: pass p covers rows p*8..p*8+7 of this wave's 32
    const int srow = lane & 7;          // row within pass
    const int g8   = lane >> 3;         // 32B col-chunk 0..7
    const int sks  = g8 >> 2, squad = g8 & 3;

    const unsigned short* Wt = (const unsigned short*)Wsrc;
    const float* Wf = (const float*)Wsrc;

    floatx4 acc[2][4];                  // [mt][ni]
#pragma unroll
    for (int i = 0; i < 2; i++)
#pragma unroll
        for (int j = 0; j < 4; j++) acc[i][j] = (floatx4){0.f, 0.f, 0.f, 0.f};

    floatx4 la[4][2];                   // staged A: 4 passes x 8 floats

    const float* xbase = X + (size_t)(m0 + wm * 32 + srow) * ROWLEN + obase + g8 * 8;

    auto stage_load = [&](int slab) {
        bool valid = !((s == 0 && slab < 2) || (s == SEQ - 1 && slab >= 4));
        if (valid) {
#pragma unroll
            for (int p = 0; p < 4; p++) {
                const float* b = xbase + (size_t)(p * 8) * ROWLEN + slab * 64;
                la[p][0] = *reinterpret_cast<const floatx4*>(b);
                la[p][1] = *reinterpret_cast<const floatx4*>(b + 4);
            }
        } else {
#pragma unroll
            for (int p = 0; p < 4; p++) {
                la[p][0] = (floatx4){0.f, 0.f, 0.f, 0.f};
                la[p][1] = (floatx4){0.f, 0.f, 0.f, 0.f};
            }
        }
    };
    auto stage_write = [&](int buf) {
#pragma unroll
        for (int p = 0; p < 4; p++) {
            int r = p * 8 + srow;                     // 0..31
            int mt = r >> 4, r15 = r & 15;
            ushortx8 v;
#pragma unroll
            for (int j = 0; j < 4; j++) {
                v[j]     = f2bf(la[p][0][j]);
                v[4 + j] = f2bf(la[p][1][j]);
            }
            *reinterpret_cast<ushortx8*>(
                &Alds[wv][buf][sks][mt][(r15 + 16 * squad) * 8]) = v;
        }
    };
    auto compute = [&](int buf, int slab) {
        bf16x8 bq[2][4], af[2][2];
        if (USE_WT) {
            const unsigned short* bsrc =
                Wt + ((size_t)(s * 6 + slab)) * 8192 + (size_t)(wn * 4) * 512 + lane * 8;
#pragma unroll
            for (int ks = 0; ks < 2; ks++)
#pragma unroll
                for (int ni = 0; ni < 4; ni++)
                    bq[ks][ni] = *reinterpret_cast<const bf16x8*>(
                        bsrc + (ks * 8 + ni) * 512);
        } else {
#pragma unroll
            for (int ks = 0; ks < 2; ks++)
#pragma unroll
                for (int ni = 0; ni < 4; ni++) {
                    int n = wn * 64 + ni * 16 + colq;
                    int k = slab * 64 + ks * 32 + quad * 8;
                    ushortx8 v;
#pragma unroll
                    for (int j = 0; j < 8; j++)
                        v[j] = f2bf(Wf[((size_t)s * KDIM + k + j) * FEAT + n]);
                    bq[ks][ni] = __builtin_bit_cast(bf16x8, v);
                }
        }
#pragma unroll
        for (int ks = 0; ks < 2; ks++)
#pragma unroll
            for (int mt = 0; mt < 2; mt++)
                af[ks][mt] = *reinterpret_cast<const bf16x8*>(
                    &Alds[wv][buf][ks][mt][lane * 8]);
#pragma unroll
        for (int ks = 0; ks < 2; ks++)
#pragma unroll
            for (int mt = 0; mt < 2; mt++)
#pragma unroll
                for (int ni = 0; ni < 4; ni++)
                    acc[mt][ni] = __builtin_amdgcn_mfma_f32_16x16x32_bf16(
                        af[ks][mt], bq[ks][ni], acc[mt][ni], 0, 0, 0);
    };

    // prologue
    stage_load(0);
    stage_write(0);

#pragma unroll 2
    for (int i = 0; i < 6; i++) {
        if (i < 5) stage_load(i + 1);        // issue next slab's global loads
        compute(i & 1, i);                   // B L2 loads + private ds_reads + 16 MFMA
        if (i < 5) stage_write((i + 1) & 1); // cvt + write private other buffer
    }

    // epilogue: bias + relu; C layout: col=lane&15, row=quad*4+reg (verified)
#pragma unroll
    for (int mt = 0; mt < 2; mt++) {
        int m = m0 + wm * 32 + mt * 16 + quad * 4;
#pragma unroll
        for (int ni = 0; ni < 4; ni++) {
            int n = wn * 64 + ni * 16 + colq;
            float bv = bias[s * FEAT + n];
#pragma unroll
            for (int r = 0; r < 4; r++) {
                float v = acc[mt][ni][r] + bv;
                v = v > 0.f ? v : 0.f;
                out[((size_t)(m + r) * SEQ + s) * FEAT + n] = v;
            }
        }
    }
}

extern "C" void kernel_launch(void* const* d_in, const int* in_sizes, int n_in,
                              void* d_out, int out_size, void* d_ws, size_t ws_size,
                              hipStream_t stream) {
    const float* X    = (const float*)d_in[0];
    const float* W    = (const float*)d_in[1];
    const float* bias = (const float*)d_in[2];
    float* out = (float*)d_out;

    const int B = in_sizes[0] / ROWLEN;               // 4096
    dim3 grid(B / BM, SEQ);                           // m-fastest: same-s blocks adjacent

    const size_t wt_bytes = (size_t)SEQ * 6 * 8192 * sizeof(unsigned short);  // ~4 MB
    if (ws_size >= wt_bytes) {
        unsigned short* Wt = (unsigned short*)d_ws;
        wt3_kernel<<<SEQ * 6, 256, 0, stream>>>(W, Wt);
        gemm_kernel<1><<<grid, 256, 0, stream>>>(X, (const void*)Wt, bias, out);
    } else {
        gemm_kernel<0><<<grid, 256, 0, stream>>>(X, (const void*)W, bias, out);
    }
}